// Round 12
// baseline (1306.318 us; speedup 1.0000x reference)
//
#include <hip/hip_runtime.h>
#include <cstdint>
#include <cstddef>

// Problem constants
#define BB   32
#define CC   384
#define NN   1024
#define N1   1025
#define TT   48
#define NCLS 97
#define NBL_LD 1088   // bf16 elems per row of logits buffer (2176 B = 17*128)
#define NBTS   1056   // bf16 elems per row of transposed nb (2112 B, 16B-aligned)

static constexpr float INV_SCALE = 1.0f / 19.595917942265423f; // 1/sqrt(384)

using bf16x8 = __attribute__((ext_vector_type(8))) __bf16;
using f32x4  = __attribute__((ext_vector_type(4))) float;

// ---- d_out element offsets (fp32), in reference return order ----
static constexpr size_t OFF_LOGITS = 0;
static constexpr size_t OFF_CFEAT  = 148992;            // 32*48*97
static constexpr size_t OFF_CMAPS  = 738816;            // +32*48*384
static constexpr size_t OFF_CMASK  = 2313216;           // +32*48*1025
static constexpr size_t OFF_NB     = 2314752;           // +32*48

// ---- workspace byte offsets ----
static constexpr size_t OFF_XB     = 0;                 // bf16 [32][384][1024]
static constexpr size_t OFF_WGEM   = 25165824;          // bf16 [768][384]
static constexpr size_t OFF_BIAS   = 25755648;          // f32 [768]
static constexpr size_t OFF_G      = 25758720;          // f32 [32][384]
static constexpr size_t OFF_QSTART = 25807872;          // f32 [32][384]
static constexpr size_t OFF_KEOS   = 25857024;          // f32 [384]
static constexpr size_t OFF_STATS  = 25858560;          // f32x2 [32][1024] (max, invsum)
static constexpr size_t OFF_MAPSBF = 26120704;          // bf16 [32][48][1024]
static constexpr size_t OFF_BAR    = 29266432;          // u32 [32] per-batch barrier counters
static constexpr size_t OFF_XBT    = 29569536;          // bf16 [32][1025][384] (dead after gemm0)
static constexpr size_t OFF_NBL    = 29569536;          // bf16 [32][1025][1088] (overlays XBT)
static constexpr size_t OFF_OUT    = 100942336;         // bf16 [32][1025][768] (kfeat | tmp)
static constexpr size_t OFF_NBT    = 100942336;         // bf16 [32][1025][1056] (overlays OUT after gemm1)

__device__ __forceinline__ float bf2f(uint u) {
    union { uint i; float f; } v; v.i = u << 16; return v.f;
}
__device__ __forceinline__ ushort f2bf(float f) {
    union { float f; uint i; } v; v.f = f;
    uint r = v.i + 0x7fffu + ((v.i >> 16) & 1u);
    return (ushort)(r >> 16);
}

// async global->LDS, 16B per lane; LDS dest = wave-uniform base + lane*16
__device__ __forceinline__ void gld16(const ushort* g, ushort* l) {
    __builtin_amdgcn_global_load_lds(
        (const __attribute__((address_space(1))) uint*)g,
        (__attribute__((address_space(3))) uint*)l, 16, 0, 0);
}

// 1) convert x -> bf16 copy (same [b][c][n] layout) + per-(b,c) mean over n
__global__ __launch_bounds__(256) void k_conv_mean(
    const float* __restrict__ x, ushort* __restrict__ xb, float* __restrict__ g)
{
    int row  = blockIdx.x * 4 + (threadIdx.x >> 6);
    int lane = threadIdx.x & 63;
    const float* src = x + (size_t)row * NN;
    ushort* dst = xb + (size_t)row * NN;
    float s = 0.f;
#pragma unroll
    for (int q = 0; q < 4; q++) {
        float4 v = ((const float4*)src)[q * 64 + lane];
        s += v.x + v.y + v.z + v.w;
        ushort4 p; p.x = f2bf(v.x); p.y = f2bf(v.y); p.z = f2bf(v.z); p.w = f2bf(v.w);
        ((ushort4*)dst)[q * 64 + lane] = p;
    }
#pragma unroll
    for (int o = 32; o; o >>= 1) s += __shfl_down(s, o);
    if (lane == 0) g[row] = s * (1.0f / NN);
}

// 2) transpose xb [b][c][n] -> xbT [b][n][c] (bf16)
__global__ __launch_bounds__(256) void k_transpose(
    const ushort* __restrict__ xb, ushort* __restrict__ xbT)
{
    int b = blockIdx.z, c0 = blockIdx.x * 64, n0 = blockIdx.y * 64;
    __shared__ ushort t[64][65];
    int ur = threadIdx.x >> 5, uc = threadIdx.x & 31;
    const ushort* src = xb + ((size_t)b * CC + c0) * NN + n0;
#pragma unroll
    for (int p = 0; p < 8; p++) {
        int c = p * 8 + ur;
        uint v = ((const uint*)(src + (size_t)c * NN))[uc];
        t[c][uc * 2]     = (ushort)(v & 0xffffu);
        t[c][uc * 2 + 1] = (ushort)(v >> 16);
    }
    __syncthreads();
    ushort* dst = xbT + ((size_t)b * N1 + n0) * CC + c0;
#pragma unroll
    for (int p = 0; p < 8; p++) {
        int n = p * 8 + ur;
        uint v = (uint)t[uc * 2][n] | (((uint)t[uc * 2 + 1][n]) << 16);
        ((uint*)(dst + (size_t)n * CC))[uc] = v;
    }
}

// 3) fused setup: Wgem(k_w | W2T), bias, eos row of xbT, keos + Out eos rows, q_start
__global__ __launch_bounds__(384) void k_setup(
    const float* __restrict__ k_w, const float* __restrict__ k_b,
    const float* __restrict__ nav_w, const float* __restrict__ q_w,
    const float* __restrict__ q_b, const float* __restrict__ eos,
    const float* __restrict__ g,
    ushort* __restrict__ Wgem, float* __restrict__ bias,
    ushort* __restrict__ xbT, float* __restrict__ keos,
    ushort* __restrict__ Out, float* __restrict__ q_start)
{
    int blk = blockIdx.x, c = threadIdx.x;
    if (blk < 384) {                    // Wgem rows 0..383 = bf16(k_w); bias = k_b
        Wgem[(size_t)blk * CC + c] = f2bf(k_w[(size_t)blk * CC + c]);
        if (c == 0) bias[blk] = k_b[blk];
    } else if (blk < 768) {             // Wgem rows 384..767: W2T = nav_w^T @ q_w
        int m = blk - 384;
        float acc = 0.f, accb = 0.f;
        for (int k = 0; k < CC; k++) {
            float nv = nav_w[(size_t)k * CC + m];
            acc  += nv * q_w[(size_t)k * CC + c];
            accb += nv * q_b[k];
        }
        Wgem[(size_t)(CC + m) * CC + c] = f2bf(acc);
        if (c == 0) bias[CC + m] = accb;
    } else if (blk < 800) {             // eos row of xbT
        int b = blk - 768;
        xbT[((size_t)b * N1 + NN) * CC + c] = f2bf(eos[c]);
    } else if (blk == 800) {            // keos + bf16 eos rows of Out
        float acc = k_b[c];
        const float* w = k_w + (size_t)c * CC;
        for (int k = 0; k < CC; k++) acc += eos[k] * w[k];
        keos[c] = acc;
        ushort v = f2bf(acc);
        for (int b = 0; b < BB; b++) Out[((size_t)b * N1 + NN) * 768 + c] = v;
    } else {                            // q_start for batch blk-801
        int b = blk - 801;
        __shared__ float gs[CC];
        gs[c] = g[(size_t)b * CC + c];
        __syncthreads();
        float acc = q_b[c];
        const float* w = q_w + (size_t)c * CC;
        for (int k = 0; k < CC; k++) acc += gs[k] * w[k];
        q_start[(size_t)b * CC + c] = acc;
    }
}

// 7) bf16 MFMA GEMM, C = A @ B^T, 128x128 tile, BK=64, 4 waves.
// Staging via global_load_lds width=16: linear LDS dest + inverse-swizzled
// global source; read side applies the same XOR (T2 swizzle, rule 21).
// MODE 0: +bias (Out);  MODE 1: *INV_SCALE (nbL logits). XCD-swizzled 1D grid.
template<int MODE, int NTN, int PERB>
__global__ __launch_bounds__(256) void k_gemm(
    const ushort* __restrict__ Aall, size_t strideAb, int lda,
    const ushort* __restrict__ Ball, size_t strideBb, int ldb,
    ushort* __restrict__ Cout, size_t strideCb, int ldc,
    const float* __restrict__ bias)
{
    int wid = blockIdx.x;
    int xcd = wid & 7;
    int work = xcd * (PERB * 4) + (wid >> 3);
    int b = work / PERB;
    int r = work - b * PERB;
    int m0 = (r / NTN) * 128, n0 = (r % NTN) * 128;

    const ushort* A  = Aall + (size_t)b * strideAb;
    const ushort* Bp = Ball + (size_t)b * strideBb;
    __shared__ ushort sbuf[16384];          // As(8192) | Bs(8192); reused as 128x128 C tile
    ushort* As = sbuf;
    ushort* Bs = sbuf + 8192;
    int tid = threadIdx.x, wave = tid >> 6, lane = tid & 63;
    int wm = wave >> 1, wn = wave & 1;
    f32x4 acc[4][4] = {};

    for (int k0 = 0; k0 < CC; k0 += 64) {
        // stage: thread (q,tid) owns LDS elems idx*8.. (idx=q*256+tid); the HW
        // places lane data linearly, so fetch the inverse-swizzled source chunk.
#pragma unroll
        for (int q = 0; q < 4; q++) {
            int idx = q * 256 + tid, rr = idx >> 3, sw = idx & 7;
            int src = (sw ^ (rr & 7)) << 3;
            ushort* dA = As + (size_t)(q * 2048 + wave * 512);
            ushort* dB = Bs + (size_t)(q * 2048 + wave * 512);
            gld16(A  + (size_t)(m0 + rr) * lda + k0 + src, dA);
            gld16(Bp + (size_t)(n0 + rr) * ldb + k0 + src, dB);
        }
        __syncthreads();                    // vmcnt(0) drain + barrier
#pragma unroll
        for (int h = 0; h < 2; h++) {
            bf16x8 af[4], bfr[4];
            int chb = h * 4 + (lane >> 4);        // chunk index 0..7
#pragma unroll
            for (int i = 0; i < 4; i++) {
                int row = wm * 64 + i * 16 + (lane & 15);
                af[i]  = *(const bf16x8*)(As + row * 64 + ((chb ^ (row & 7)) << 3));
                int col = wn * 64 + i * 16 + (lane & 15);
                bfr[i] = *(const bf16x8*)(Bs + col * 64 + ((chb ^ (col & 7)) << 3));
            }
#pragma unroll
            for (int i = 0; i < 4; i++)
#pragma unroll
                for (int j = 0; j < 4; j++)
                    acc[i][j] = __builtin_amdgcn_mfma_f32_16x16x32_bf16(af[i], bfr[j], acc[i][j], 0, 0, 0);
        }
        __syncthreads();                    // protect LDS before next stage
    }
    // epilogue: stage bf16 C tile in LDS, then vectorized aligned global writes
#pragma unroll
    for (int i = 0; i < 4; i++) {
        int rl = wm * 64 + i * 16 + ((lane >> 4) << 2);
#pragma unroll
        for (int j = 0; j < 4; j++) {
            int cl = wn * 64 + j * 16 + (lane & 15);
            float bv = (MODE == 0) ? bias[n0 + cl] : 0.f;
#pragma unroll
            for (int rr = 0; rr < 4; rr++) {
                float val = (MODE == 0) ? (acc[i][j][rr] + bv) : (acc[i][j][rr] * INV_SCALE);
                sbuf[(rl + rr) * 128 + cl] = f2bf(val);
            }
        }
    }
    __syncthreads();
    ushort* Cb = Cout + (size_t)b * strideCb;
#pragma unroll
    for (int q = 0; q < 8; q++) {
        int idx = q * 256 + tid, row = idx >> 4, seg = idx & 15;
        *(uint4*)(Cb + (size_t)(m0 + row) * ldc + n0 + seg * 8) =
            *(const uint4*)(sbuf + row * 128 + seg * 8);
    }
}

// 8) start_map softmax -> char_maps[:,0,:]
__global__ __launch_bounds__(1024) void k_start(
    const ushort* __restrict__ Out, const float* __restrict__ q_start,
    float* __restrict__ cmaps)
{
    int b = blockIdx.x, tid = threadIdx.x;
    __shared__ float qs[CC];
    __shared__ float red[16];
    __shared__ float bc;
    if (tid < CC) qs[tid] = q_start[(size_t)b * CC + tid];
    __syncthreads();
    auto dot = [&](int n) {
        const uint4* row = (const uint4*)(Out + ((size_t)b * N1 + n) * 768);
        float acc = 0.f;
        for (int c8 = 0; c8 < CC / 8; c8++) {
            uint4 u = row[c8];
            const ushort* us = (const ushort*)&u;
#pragma unroll
            for (int e = 0; e < 8; e++) acc += bf2f(us[e]) * qs[c8 * 8 + e];
        }
        return acc * INV_SCALE;
    };
    float v0 = dot(tid);
    float v1 = (tid == 0) ? dot(1024) : -1e30f;
    float lm = fmaxf(v0, v1);
#pragma unroll
    for (int o = 32; o; o >>= 1) lm = fmaxf(lm, __shfl_down(lm, o));
    if ((tid & 63) == 0) red[tid >> 6] = lm;
    __syncthreads();
    if (tid == 0) { float m = red[0]; for (int i = 1; i < 16; i++) m = fmaxf(m, red[i]); bc = m; }
    __syncthreads();
    float bmax = bc;
    float e0 = __expf(v0 - bmax);
    float e1 = (tid == 0) ? __expf(v1 - bmax) : 0.f;
    float ls = e0 + e1;
#pragma unroll
    for (int o = 32; o; o >>= 1) ls += __shfl_down(ls, o);
    if ((tid & 63) == 0) red[tid >> 6] = ls;
    __syncthreads();
    if (tid == 0) { float s = 0.f; for (int i = 0; i < 16; i++) s += red[i]; bc = s; }
    __syncthreads();
    float inv = 1.f / bc;
    float* o = cmaps + ((size_t)b * TT) * N1;
    o[tid] = e0 * inv;
    if (tid == 0) o[1024] = e1 * inv;
}

// 9) eos column logits -> nbL col 1024 (bf16)
__global__ __launch_bounds__(256) void k_eoscol_nbl(
    const ushort* __restrict__ Out, const float* __restrict__ keos, ushort* __restrict__ nbL)
{
    int gw = blockIdx.x * 4 + (threadIdx.x >> 6);
    int lane = threadIdx.x & 63;
    for (int rr = 0; rr < 4; rr++) {
        int gi = gw * 4 + rr, b = gi >> 10, i = gi & 1023;
        const ushort* row = Out + ((size_t)b * N1 + i) * 768 + 384;
        float acc = 0.f;
        for (int c = lane; c < CC; c += 64) acc += bf2f(row[c]) * keos[c];
#pragma unroll
        for (int o = 32; o; o >>= 1) acc += __shfl_down(acc, o);
        if (lane == 0) nbL[((size_t)b * N1 + i) * NBL_LD + 1024] = f2bf(acc * INV_SCALE);
    }
}

// 10) row softmax from bf16 logits: write fp32 nb (d_out) + (max, invsum) stats
__global__ __launch_bounds__(256) void k_softnb2(
    const ushort* __restrict__ nbL, float* __restrict__ nb, float2* __restrict__ stats)
{
    int bi = blockIdx.x;
    int b = bi >> 10, i = bi & 1023;
    const ushort* row = nbL + ((size_t)b * N1 + i) * NBL_LD;
    int tid = threadIdx.x;
    uint2 u = *(const uint2*)(row + tid * 4);
    float v0 = bf2f(u.x & 0xffffu), v1 = bf2f(u.x >> 16);
    float v2 = bf2f(u.y & 0xffffu), v3 = bf2f(u.y >> 16);
    float vt = (tid == 0) ? bf2f(row[1024]) : -1e30f;
    __shared__ float r1[4]; __shared__ float bc;
    float lm = fmaxf(fmaxf(fmaxf(v0, v1), fmaxf(v2, v3)), vt);
#pragma unroll
    for (int o = 32; o; o >>= 1) lm = fmaxf(lm, __shfl_down(lm, o));
    if ((tid & 63) == 0) r1[tid >> 6] = lm;
    __syncthreads();
    if (tid == 0) bc = fmaxf(fmaxf(r1[0], r1[1]), fmaxf(r1[2], r1[3]));
    __syncthreads();
    float m = bc;
    float e0 = __expf(v0 - m), e1 = __expf(v1 - m), e2 = __expf(v2 - m), e3 = __expf(v3 - m);
    float et = (tid == 0) ? __expf(vt - m) : 0.f;
    float s = e0 + e1 + e2 + e3 + et;
#pragma unroll
    for (int o = 32; o; o >>= 1) s += __shfl_down(s, o);
    if ((tid & 63) == 0) r1[tid >> 6] = s;
    __syncthreads();
    if (tid == 0) bc = r1[0] + r1[1] + r1[2] + r1[3];
    __syncthreads();
    float inv = 1.f / bc;
    float* orow = nb + ((size_t)b * N1 + i) * N1;
    float4 ov = make_float4(e0 * inv, e1 * inv, e2 * inv, e3 * inv);
    *(float4*)(orow + tid * 4) = ov;
    if (tid == 0) { orow[1024] = et * inv; stats[b * 1024 + i] = make_float2(m, inv); }
}

// 11) one-hot row 1024 of nb (d_out)
__global__ void k_onehot(float* __restrict__ nb)
{
    int b = blockIdx.x;
    float* row = nb + ((size_t)b * N1 + NN) * N1;
    for (int j = threadIdx.x; j < N1; j += 256)
        row[j] = (j == 1024) ? 1.f : 0.f;
}

// 12) transpose: nbL (bf16 logits) + stats -> nbT bf16 [b][j][n] (probabilities)
__global__ __launch_bounds__(256) void k_transq(
    const ushort* __restrict__ nbL, const float2* __restrict__ stats,
    ushort* __restrict__ nbT)
{
    int b = blockIdx.z, n0 = blockIdx.x * 64, j0 = blockIdx.y * 64;
    __shared__ ushort tile[64][80];   // [j_local][n_local]
    __shared__ float2 st[64];
    int tid = threadIdx.x;
    if (tid < 64) st[tid] = stats[b * 1024 + n0 + tid];
    __syncthreads();
#pragma unroll
    for (int q = 0; q < 2; q++) {
        int idx = q * 256 + tid, rl = idx >> 3, ch = idx & 7;  // rl = n_local
        const ushort* src = nbL + ((size_t)b * N1 + n0 + rl) * NBL_LD + j0 + ch * 8;
        uint4 u = *(const uint4*)src;
        float2 s = st[rl];
        const ushort* us = (const ushort*)&u;
#pragma unroll
        for (int k = 0; k < 8; k++)
            tile[ch * 8 + k][rl] = f2bf(__expf(bf2f(us[k]) - s.x) * s.y);
    }
    __syncthreads();
#pragma unroll
    for (int q = 0; q < 2; q++) {
        int idx = q * 256 + tid, jl = idx >> 3, seg = idx & 7;
        int j = j0 + jl;
        if (j <= 1024) {
            uint4 v = *(const uint4*)&tile[jl][seg * 8];
            *(uint4*)(nbT + ((size_t)b * N1 + j) * NBTS + n0 + seg * 8) = v;
        }
    }
}

// 13a) reset per-batch barrier counters
__global__ void k_barinit(uint* __restrict__ bar) { bar[threadIdx.x] = 0u; }

__device__ __forceinline__ float dot16(uint4 r0, uint4 r1,
                                       const float* cA, const float* cB)
{
    const ushort* p0 = (const ushort*)&r0;
    const ushort* p1 = (const ushort*)&r1;
    float acc = 0.f;
#pragma unroll
    for (int e = 0; e < 8; e++) acc += bf2f(p0[e]) * cA[e];
#pragma unroll
    for (int e = 0; e < 8; e++) acc += bf2f(p1[e]) * cB[e];
    return acc;
}

// 13b) persistent fused recurrence v2: 256 blocks (8/batch, 1/CU) x 512 threads.
// nbT rows live in VGPRs for all 47 steps (128 rows/block = 128 VGPRs/lane of
// data; loaded ONCE). Per step: read m_t (4KB), cmd=expm1(kk*m) + sum in LDS,
// register dots, write m_{t+1}, then a per-batch barrier with RELAXED spin and
// a SINGLE release/acquire fence pair (round-8's acquire-per-poll L2 thrash
// eliminated; rows never touch memory again).
__global__ __launch_bounds__(512, 2) void k_rec2(
    float* __restrict__ cmaps, const ushort* __restrict__ nbT, uint* __restrict__ bar)
{
    int blk = blockIdx.x;
    int b = blk >> 3, chunk = blk & 7;
    int tid = threadIdx.x, wave = tid >> 6, lane = tid & 63;
    int jbase = chunk * 128 + wave * 16;
    const ushort* base = nbT + (size_t)b * N1 * NBTS;

    // load this block's 128 rows into registers (once)
    uint4 rv[16][2];
#pragma unroll
    for (int r = 0; r < 16; ++r) {
        const ushort* row = base + (size_t)(jbase + r) * NBTS;
        rv[r][0] = *(const uint4*)(row + lane * 8);
        rv[r][1] = *(const uint4*)(row + 512 + lane * 8);
    }
    bool hasE = (chunk == 7 && wave == 7);   // extra eos row j=1024
    uint4 rvE0 = {}, rvE1 = {};
    if (hasE) {
        const ushort* row = base + (size_t)1024 * NBTS;
        rvE0 = *(const uint4*)(row + lane * 8);
        rvE1 = *(const uint4*)(row + 512 + lane * 8);
    }

    __shared__ __align__(16) float cmd[1028];
    __shared__ float red[8];
    __shared__ float sinvS;

    for (int t = 0; t < TT - 1; ++t) {
        const float* mrow = cmaps + ((size_t)b * TT + t) * N1;
        int kki = 1 + 2 * t; if (kki > 16) kki = 16;
        float kkf = (float)kki;
        float m0 = __hip_atomic_load(mrow + tid, __ATOMIC_RELAXED, __HIP_MEMORY_SCOPE_AGENT);
        float m1 = __hip_atomic_load(mrow + 512 + tid, __ATOMIC_RELAXED, __HIP_MEMORY_SCOPE_AGENT);
        float c0 = expm1f(kkf * m0), c1 = expm1f(kkf * m1);
        cmd[tid] = c0; cmd[512 + tid] = c1;
        float part = c0 + c1;
        if (tid == 0) {
            float mt = __hip_atomic_load(mrow + 1024, __ATOMIC_RELAXED, __HIP_MEMORY_SCOPE_AGENT);
            float ct = expm1f(kkf * mt);
            cmd[1024] = ct; part += ct;
        }
#pragma unroll
        for (int o = 32; o; o >>= 1) part += __shfl_down(part, o);
        if (lane == 0) red[wave] = part;
        __syncthreads();
        if (tid == 0) {
            float s = 0.f;
#pragma unroll
            for (int w = 0; w < 8; w++) s += red[w];
            sinvS = 1.f / s;
        }
        __syncthreads();
        float inv = sinvS;
        float cA[8], cB[8];
        *(float4*)&cA[0] = *(const float4*)(cmd + lane * 8);
        *(float4*)&cA[4] = *(const float4*)(cmd + lane * 8 + 4);
        *(float4*)&cB[0] = *(const float4*)(cmd + 512 + lane * 8);
        *(float4*)&cB[4] = *(const float4*)(cmd + 512 + lane * 8 + 4);
        float ctail = cmd[1024];
        float* orow = cmaps + ((size_t)b * TT + t + 1) * N1;
#pragma unroll
        for (int r = 0; r < 16; ++r) {
            float a = dot16(rv[r][0], rv[r][1], cA, cB);
#pragma unroll
            for (int o = 32; o; o >>= 1) a += __shfl_down(a, o);
            if (lane == 0)
                __hip_atomic_store(orow + jbase + r, a * inv,
                                   __ATOMIC_RELAXED, __HIP_MEMORY_SCOPE_AGENT);
        }
        if (hasE) {
            float a = dot16(rvE0, rvE1, cA, cB);
#pragma unroll
            for (int o = 32; o; o >>= 1) a += __shfl_down(a, o);
            if (lane == 0)
                __hip_atomic_store(orow + 1024, (a + ctail) * inv,
                                   __ATOMIC_RELAXED, __HIP_MEMORY_SCOPE_AGENT);
        }
        __syncthreads();                   // all waves done writing + reading cmd
        if (tid == 0) {
            __builtin_amdgcn_fence(__ATOMIC_RELEASE, "agent");
            __hip_atomic_fetch_add(&bar[b], 1u, __ATOMIC_RELAXED, __HIP_MEMORY_SCOPE_AGENT);
            uint want = 8u * (uint)(t + 1);
            while (__hip_atomic_load(&bar[b], __ATOMIC_RELAXED, __HIP_MEMORY_SCOPE_AGENT) < want)
                __builtin_amdgcn_s_sleep(2);
            __builtin_amdgcn_fence(__ATOMIC_ACQUIRE, "agent");
        }
        __syncthreads();
    }
}

// 14) masks
__global__ void k_masks(const float* __restrict__ cmaps, float* __restrict__ cmask)
{
    int b = threadIdx.x;
    if (b < BB) {
        int fin = 0;
        for (int t = 0; t < TT; t++) {
            cmask[b * TT + t] = (fin == 0) ? 1.f : 0.f;
            fin += (cmaps[((size_t)b * TT + t) * N1 + 1024] > 0.6f) ? 1 : 0;
        }
    }
}

// 15) maps -> bf16 (n<1024), stride 1024
__global__ void k_mapsbf(const float* __restrict__ cmaps, ushort* __restrict__ mb)
{
    size_t i = (size_t)blockIdx.x * 256 + threadIdx.x;
    size_t bt = i >> 10; int n = (int)(i & 1023);
    mb[i] = f2bf(cmaps[bt * N1 + n]);
}

// 16) char_feats
__global__ __launch_bounds__(256) void k_cfeat(
    const ushort* __restrict__ mapsbf, const ushort* __restrict__ xb,
    const float* __restrict__ cmaps, const float* __restrict__ eos,
    const float* __restrict__ masks, float* __restrict__ cfeat)
{
    int b = blockIdx.x;
    int wave = threadIdx.x >> 6, lane = threadIdx.x & 63;
    f32x4 acc[3][6] = {};
    const ushort* Ab = mapsbf + (size_t)b * TT * 1024;
    const ushort* Bb = xb + (size_t)b * CC * NN;
    for (int k0 = 0; k0 < NN; k0 += 32) {
        int kk_ = k0 + (lane >> 4) * 8;
        bf16x8 af[3], bfr[6];
#pragma unroll
        for (int i = 0; i < 3; i++)
            af[i] = *(const bf16x8*)(Ab + (size_t)(i * 16 + (lane & 15)) * 1024 + kk_);
#pragma unroll
        for (int j = 0; j < 6; j++)
            bfr[j] = *(const bf16x8*)(Bb + (size_t)(wave * 96 + j * 16 + (lane & 15)) * NN + kk_);
#pragma unroll
        for (int i = 0; i < 3; i++)
#pragma unroll
            for (int j = 0; j < 6; j++)
                acc[i][j] = __builtin_amdgcn_mfma_f32_16x16x32_bf16(af[i], bfr[j], acc[i][j], 0, 0, 0);
    }
#pragma unroll
    for (int i = 0; i < 3; i++) {
        int tbase = i * 16 + ((lane >> 4) << 2);
#pragma unroll
        for (int j = 0; j < 6; j++) {
            int c = wave * 96 + j * 16 + (lane & 15);
            float ev = eos[c];
#pragma unroll
            for (int rr = 0; rr < 4; rr++) {
                int tt = tbase + rr;
                float mlast = cmaps[((size_t)b * TT + tt) * N1 + 1024];
                float val = (acc[i][j][rr] + mlast * ev) * masks[b * TT + tt];
                cfeat[((size_t)b * TT + tt) * CC + c] = val;
            }
        }
    }
}

// 17) logits
__global__ __launch_bounds__(128) void k_logits(
    const float* __restrict__ cfeat, const float* __restrict__ cls_w,
    const float* __restrict__ cls_b, float* __restrict__ out)
{
    int bt = blockIdx.x;
    __shared__ float row[CC];
    for (int c = threadIdx.x; c < CC; c += 128) row[c] = cfeat[(size_t)bt * CC + c];
    __syncthreads();
    int j = threadIdx.x;
    if (j < NCLS) {
        float acc = cls_b[j];
        const float* w = cls_w + (size_t)j * CC;
        for (int c = 0; c < CC; c++) acc += row[c] * w[c];
        out[(size_t)bt * NCLS + j] = acc;
    }
}

extern "C" void kernel_launch(void* const* d_in, const int* in_sizes, int n_in,
                              void* d_out, int out_size, void* d_ws, size_t ws_size,
                              hipStream_t stream)
{
    (void)in_sizes; (void)n_in; (void)out_size; (void)ws_size;
    const float* x     = (const float*)d_in[0];
    const float* eos   = (const float*)d_in[1];
    const float* q_w   = (const float*)d_in[2];
    const float* q_b   = (const float*)d_in[3];
    const float* k_w   = (const float*)d_in[4];
    const float* k_b   = (const float*)d_in[5];
    const float* nav_w = (const float*)d_in[6];
    const float* cls_w = (const float*)d_in[8];
    const float* cls_b = (const float*)d_in[9];
    // nav_b (d_in[7]) is a constant shift before softmax -> no effect on outputs

    char* ws = (char*)d_ws;
    ushort* xb     = (ushort*)(ws + OFF_XB);
    ushort* Wgem   = (ushort*)(ws + OFF_WGEM);
    float*  bias   = (float*)(ws + OFF_BIAS);
    float*  g      = (float*)(ws + OFF_G);
    float*  qstart = (float*)(ws + OFF_QSTART);
    float*  keos   = (float*)(ws + OFF_KEOS);
    float2* stats  = (float2*)(ws + OFF_STATS);
    ushort* mapsbf = (ushort*)(ws + OFF_MAPSBF);
    uint*   bar    = (uint*)(ws + OFF_BAR);
    ushort* xbT    = (ushort*)(ws + OFF_XBT);
    ushort* nbL    = (ushort*)(ws + OFF_NBL);
    ushort* Out    = (ushort*)(ws + OFF_OUT);
    ushort* nbT    = (ushort*)(ws + OFF_NBT);

    float* out     = (float*)d_out;
    float* logits  = out + OFF_LOGITS;
    float* cfeat   = out + OFF_CFEAT;
    float* cmaps   = out + OFF_CMAPS;
    float* cmask   = out + OFF_CMASK;
    float* nb      = out + OFF_NB;

    k_conv_mean<<<3072, 256, 0, stream>>>(x, xb, g);
    k_transpose<<<dim3(6, 16, BB), 256, 0, stream>>>(xb, xbT);
    k_setup<<<833, 384, 0, stream>>>(k_w, k_b, nav_w, q_w, q_b, eos, g,
                                     Wgem, bias, xbT, keos, Out, qstart);
    k_barinit<<<1, 32, 0, stream>>>(bar);

    // Out[:, :1024, :768] = xt @ [k_w | W2]^T + bias (kfeat | tmp), bf16
    k_gemm<0, 6, 48><<<1536, 256, 0, stream>>>(
        xbT, (size_t)N1 * CC, CC, Wgem, 0, CC, Out, (size_t)N1 * 768, 768, bias);

    k_start<<<BB, 1024, 0, stream>>>(Out, qstart, cmaps);
    k_eoscol_nbl<<<2048, 256, 0, stream>>>(Out, keos, nbL);

    // nb logits (cols 0..1023) = tmp @ kfeat^T / scale, bf16 into nbL (ld 1088)
    k_gemm<1, 8, 64><<<2048, 256, 0, stream>>>(
        Out + 384, (size_t)N1 * 768, 768, Out, (size_t)N1 * 768, 768,
        nbL, (size_t)N1 * NBL_LD, NBL_LD, nullptr);

    k_softnb2<<<BB * NN, 256, 0, stream>>>(nbL, nb, stats);
    k_onehot<<<BB, 256, 0, stream>>>(nb);
    k_transq<<<dim3(16, 17, BB), 256, 0, stream>>>(nbL, stats, nbT);

    // fused 47-step recurrence: one persistent dispatch, rows in VGPRs
    k_rec2<<<256, 512, 0, stream>>>(cmaps, nbT, bar);

    k_masks<<<1, 64, 0, stream>>>(cmaps, cmask);
    k_mapsbf<<<6144, 256, 0, stream>>>(cmaps, mapsbf);
    k_cfeat<<<BB, 256, 0, stream>>>(mapsbf, xb, cmaps, eos, cmask, cfeat);
    k_logits<<<BB * TT, 128, 0, stream>>>(cfeat, cls_w, cls_b, logits);
}

// Round 13
// 1003.619 us; speedup vs baseline: 1.3016x; 1.3016x over previous
//
#include <hip/hip_runtime.h>
#include <cstdint>
#include <cstddef>

// Problem constants
#define BB   32
#define CC   384
#define NN   1024
#define N1   1025
#define TT   48
#define NCLS 97
#define NBL_LD 1088   // bf16 elems per row of logits buffer (2176 B = 17*128)
#define NBTS   1056   // bf16 elems per row of transposed nb (2112 B, 16B-aligned)
#define NBQS   1056   // bytes per row of int8 nbQ

static constexpr float INV_SCALE = 1.0f / 19.595917942265423f; // 1/sqrt(384)

using bf16x8 = __attribute__((ext_vector_type(8))) __bf16;
using f32x4  = __attribute__((ext_vector_type(4))) float;

// ---- d_out element offsets (fp32), in reference return order ----
static constexpr size_t OFF_LOGITS = 0;
static constexpr size_t OFF_CFEAT  = 148992;            // 32*48*97
static constexpr size_t OFF_CMAPS  = 738816;            // +32*48*384
static constexpr size_t OFF_CMASK  = 2313216;           // +32*48*1025
static constexpr size_t OFF_NB     = 2314752;           // +32*48

// ---- workspace byte offsets ----
static constexpr size_t OFF_XB     = 0;                 // bf16 [32][384][1024]
static constexpr size_t OFF_WGEM   = 25165824;          // bf16 [768][384]
static constexpr size_t OFF_BIAS   = 25755648;          // f32 [768]
static constexpr size_t OFF_G      = 25758720;          // f32 [32][384]
static constexpr size_t OFF_QSTART = 25807872;          // f32 [32][384]
static constexpr size_t OFF_KEOS   = 25857024;          // f32 [384]
static constexpr size_t OFF_STATS  = 25858560;          // f32x2 [32][1024] (max, invsum)
static constexpr size_t OFF_MAPSBF = 26120704;          // bf16 [32][48][1024]
static constexpr size_t OFF_CMD    = 29266432;          // f32 2 x [32][1056] cmd double-buffer
static constexpr size_t OFF_PSUM   = 29536768;          // f32 2 x [32][128] partial sums
static constexpr size_t OFF_XBT    = 29569536;          // bf16 [32][1025][384] (dead after gemm0)
static constexpr size_t OFF_NBL    = 29569536;          // bf16 [32][1025][1088] (overlays XBT)
static constexpr size_t OFF_NBQ    = 29569536;          // int8 [32][1025][1056] (overlays NBL after transq)
static constexpr size_t OFF_SCL    = 64206336;          // f32 [32][1056] row scales
static constexpr size_t OFF_OUT    = 100942336;         // bf16 [32][1025][768] (kfeat | tmp)
static constexpr size_t OFF_NBT    = 100942336;         // bf16 [32][1025][1056] (overlays OUT after gemm1)

__device__ __forceinline__ float bf2f(uint u) {
    union { uint i; float f; } v; v.i = u << 16; return v.f;
}
__device__ __forceinline__ ushort f2bf(float f) {
    union { float f; uint i; } v; v.f = f;
    uint r = v.i + 0x7fffu + ((v.i >> 16) & 1u);
    return (ushort)(r >> 16);
}

// async global->LDS, 16B per lane; LDS dest = wave-uniform base + lane*16
__device__ __forceinline__ void gld16(const ushort* g, ushort* l) {
    __builtin_amdgcn_global_load_lds(
        (const __attribute__((address_space(1))) uint*)g,
        (__attribute__((address_space(3))) uint*)l, 16, 0, 0);
}

// 1) convert x -> bf16 copy (same [b][c][n] layout) + per-(b,c) mean over n
__global__ __launch_bounds__(256) void k_conv_mean(
    const float* __restrict__ x, ushort* __restrict__ xb, float* __restrict__ g)
{
    int row  = blockIdx.x * 4 + (threadIdx.x >> 6);
    int lane = threadIdx.x & 63;
    const float* src = x + (size_t)row * NN;
    ushort* dst = xb + (size_t)row * NN;
    float s = 0.f;
#pragma unroll
    for (int q = 0; q < 4; q++) {
        float4 v = ((const float4*)src)[q * 64 + lane];
        s += v.x + v.y + v.z + v.w;
        ushort4 p; p.x = f2bf(v.x); p.y = f2bf(v.y); p.z = f2bf(v.z); p.w = f2bf(v.w);
        ((ushort4*)dst)[q * 64 + lane] = p;
    }
#pragma unroll
    for (int o = 32; o; o >>= 1) s += __shfl_down(s, o);
    if (lane == 0) g[row] = s * (1.0f / NN);
}

// 2) transpose xb [b][c][n] -> xbT [b][n][c] (bf16)
__global__ __launch_bounds__(256) void k_transpose(
    const ushort* __restrict__ xb, ushort* __restrict__ xbT)
{
    int b = blockIdx.z, c0 = blockIdx.x * 64, n0 = blockIdx.y * 64;
    __shared__ ushort t[64][65];
    int ur = threadIdx.x >> 5, uc = threadIdx.x & 31;
    const ushort* src = xb + ((size_t)b * CC + c0) * NN + n0;
#pragma unroll
    for (int p = 0; p < 8; p++) {
        int c = p * 8 + ur;
        uint v = ((const uint*)(src + (size_t)c * NN))[uc];
        t[c][uc * 2]     = (ushort)(v & 0xffffu);
        t[c][uc * 2 + 1] = (ushort)(v >> 16);
    }
    __syncthreads();
    ushort* dst = xbT + ((size_t)b * N1 + n0) * CC + c0;
#pragma unroll
    for (int p = 0; p < 8; p++) {
        int n = p * 8 + ur;
        uint v = (uint)t[uc * 2][n] | (((uint)t[uc * 2 + 1][n]) << 16);
        ((uint*)(dst + (size_t)n * CC))[uc] = v;
    }
}

// 3) fused setup: Wgem(k_w | W2T), bias, eos row of xbT, keos + Out eos rows, q_start
__global__ __launch_bounds__(384) void k_setup(
    const float* __restrict__ k_w, const float* __restrict__ k_b,
    const float* __restrict__ nav_w, const float* __restrict__ q_w,
    const float* __restrict__ q_b, const float* __restrict__ eos,
    const float* __restrict__ g,
    ushort* __restrict__ Wgem, float* __restrict__ bias,
    ushort* __restrict__ xbT, float* __restrict__ keos,
    ushort* __restrict__ Out, float* __restrict__ q_start)
{
    int blk = blockIdx.x, c = threadIdx.x;
    if (blk < 384) {                    // Wgem rows 0..383 = bf16(k_w); bias = k_b
        Wgem[(size_t)blk * CC + c] = f2bf(k_w[(size_t)blk * CC + c]);
        if (c == 0) bias[blk] = k_b[blk];
    } else if (blk < 768) {             // Wgem rows 384..767: W2T = nav_w^T @ q_w
        int m = blk - 384;
        float acc = 0.f, accb = 0.f;
        for (int k = 0; k < CC; k++) {
            float nv = nav_w[(size_t)k * CC + m];
            acc  += nv * q_w[(size_t)k * CC + c];
            accb += nv * q_b[k];
        }
        Wgem[(size_t)(CC + m) * CC + c] = f2bf(acc);
        if (c == 0) bias[CC + m] = accb;
    } else if (blk < 800) {             // eos row of xbT
        int b = blk - 768;
        xbT[((size_t)b * N1 + NN) * CC + c] = f2bf(eos[c]);
    } else if (blk == 800) {            // keos + bf16 eos rows of Out
        float acc = k_b[c];
        const float* w = k_w + (size_t)c * CC;
        for (int k = 0; k < CC; k++) acc += eos[k] * w[k];
        keos[c] = acc;
        ushort v = f2bf(acc);
        for (int b = 0; b < BB; b++) Out[((size_t)b * N1 + NN) * 768 + c] = v;
    } else {                            // q_start for batch blk-801
        int b = blk - 801;
        __shared__ float gs[CC];
        gs[c] = g[(size_t)b * CC + c];
        __syncthreads();
        float acc = q_b[c];
        const float* w = q_w + (size_t)c * CC;
        for (int k = 0; k < CC; k++) acc += gs[k] * w[k];
        q_start[(size_t)b * CC + c] = acc;
    }
}

// 7) bf16 MFMA GEMM, C = A @ B^T, 128x128 tile, BK=64, 4 waves.
// Staging via global_load_lds width=16: linear LDS dest + inverse-swizzled
// global source; read side applies the same XOR (T2 swizzle, rule 21).
// MODE 0: +bias (Out);  MODE 1: *INV_SCALE (nbL logits). XCD-swizzled 1D grid.
template<int MODE, int NTN, int PERB>
__global__ __launch_bounds__(256) void k_gemm(
    const ushort* __restrict__ Aall, size_t strideAb, int lda,
    const ushort* __restrict__ Ball, size_t strideBb, int ldb,
    ushort* __restrict__ Cout, size_t strideCb, int ldc,
    const float* __restrict__ bias)
{
    int wid = blockIdx.x;
    int xcd = wid & 7;
    int work = xcd * (PERB * 4) + (wid >> 3);
    int b = work / PERB;
    int r = work - b * PERB;
    int m0 = (r / NTN) * 128, n0 = (r % NTN) * 128;

    const ushort* A  = Aall + (size_t)b * strideAb;
    const ushort* Bp = Ball + (size_t)b * strideBb;
    __shared__ ushort sbuf[16384];          // As(8192) | Bs(8192); reused as 128x128 C tile
    ushort* As = sbuf;
    ushort* Bs = sbuf + 8192;
    int tid = threadIdx.x, wave = tid >> 6, lane = tid & 63;
    int wm = wave >> 1, wn = wave & 1;
    f32x4 acc[4][4] = {};

    for (int k0 = 0; k0 < CC; k0 += 64) {
#pragma unroll
        for (int q = 0; q < 4; q++) {
            int idx = q * 256 + tid, rr = idx >> 3, sw = idx & 7;
            int src = (sw ^ (rr & 7)) << 3;
            ushort* dA = As + (size_t)(q * 2048 + wave * 512);
            ushort* dB = Bs + (size_t)(q * 2048 + wave * 512);
            gld16(A  + (size_t)(m0 + rr) * lda + k0 + src, dA);
            gld16(Bp + (size_t)(n0 + rr) * ldb + k0 + src, dB);
        }
        __syncthreads();                    // vmcnt(0) drain + barrier
#pragma unroll
        for (int h = 0; h < 2; h++) {
            bf16x8 af[4], bfr[4];
            int chb = h * 4 + (lane >> 4);        // chunk index 0..7
#pragma unroll
            for (int i = 0; i < 4; i++) {
                int row = wm * 64 + i * 16 + (lane & 15);
                af[i]  = *(const bf16x8*)(As + row * 64 + ((chb ^ (row & 7)) << 3));
                int col = wn * 64 + i * 16 + (lane & 15);
                bfr[i] = *(const bf16x8*)(Bs + col * 64 + ((chb ^ (col & 7)) << 3));
            }
#pragma unroll
            for (int i = 0; i < 4; i++)
#pragma unroll
                for (int j = 0; j < 4; j++)
                    acc[i][j] = __builtin_amdgcn_mfma_f32_16x16x32_bf16(af[i], bfr[j], acc[i][j], 0, 0, 0);
        }
        __syncthreads();                    // protect LDS before next stage
    }
    // epilogue: stage bf16 C tile in LDS, then vectorized aligned global writes
#pragma unroll
    for (int i = 0; i < 4; i++) {
        int rl = wm * 64 + i * 16 + ((lane >> 4) << 2);
#pragma unroll
        for (int j = 0; j < 4; j++) {
            int cl = wn * 64 + j * 16 + (lane & 15);
            float bv = (MODE == 0) ? bias[n0 + cl] : 0.f;
#pragma unroll
            for (int rr = 0; rr < 4; rr++) {
                float val = (MODE == 0) ? (acc[i][j][rr] + bv) : (acc[i][j][rr] * INV_SCALE);
                sbuf[(rl + rr) * 128 + cl] = f2bf(val);
            }
        }
    }
    __syncthreads();
    ushort* Cb = Cout + (size_t)b * strideCb;
#pragma unroll
    for (int q = 0; q < 8; q++) {
        int idx = q * 256 + tid, row = idx >> 4, seg = idx & 15;
        *(uint4*)(Cb + (size_t)(m0 + row) * ldc + n0 + seg * 8) =
            *(const uint4*)(sbuf + row * 128 + seg * 8);
    }
}

// 8) start_map softmax -> char_maps[:,0,:]
__global__ __launch_bounds__(1024) void k_start(
    const ushort* __restrict__ Out, const float* __restrict__ q_start,
    float* __restrict__ cmaps)
{
    int b = blockIdx.x, tid = threadIdx.x;
    __shared__ float qs[CC];
    __shared__ float red[16];
    __shared__ float bc;
    if (tid < CC) qs[tid] = q_start[(size_t)b * CC + tid];
    __syncthreads();
    auto dot = [&](int n) {
        const uint4* row = (const uint4*)(Out + ((size_t)b * N1 + n) * 768);
        float acc = 0.f;
        for (int c8 = 0; c8 < CC / 8; c8++) {
            uint4 u = row[c8];
            const ushort* us = (const ushort*)&u;
#pragma unroll
            for (int e = 0; e < 8; e++) acc += bf2f(us[e]) * qs[c8 * 8 + e];
        }
        return acc * INV_SCALE;
    };
    float v0 = dot(tid);
    float v1 = (tid == 0) ? dot(1024) : -1e30f;
    float lm = fmaxf(v0, v1);
#pragma unroll
    for (int o = 32; o; o >>= 1) lm = fmaxf(lm, __shfl_down(lm, o));
    if ((tid & 63) == 0) red[tid >> 6] = lm;
    __syncthreads();
    if (tid == 0) { float m = red[0]; for (int i = 1; i < 16; i++) m = fmaxf(m, red[i]); bc = m; }
    __syncthreads();
    float bmax = bc;
    float e0 = __expf(v0 - bmax);
    float e1 = (tid == 0) ? __expf(v1 - bmax) : 0.f;
    float ls = e0 + e1;
#pragma unroll
    for (int o = 32; o; o >>= 1) ls += __shfl_down(ls, o);
    if ((tid & 63) == 0) red[tid >> 6] = ls;
    __syncthreads();
    if (tid == 0) { float s = 0.f; for (int i = 0; i < 16; i++) s += red[i]; bc = s; }
    __syncthreads();
    float inv = 1.f / bc;
    float* o = cmaps + ((size_t)b * TT) * N1;
    o[tid] = e0 * inv;
    if (tid == 0) o[1024] = e1 * inv;
}

// 9) eos column logits -> nbL col 1024 (bf16)
__global__ __launch_bounds__(256) void k_eoscol_nbl(
    const ushort* __restrict__ Out, const float* __restrict__ keos, ushort* __restrict__ nbL)
{
    int gw = blockIdx.x * 4 + (threadIdx.x >> 6);
    int lane = threadIdx.x & 63;
    for (int rr = 0; rr < 4; rr++) {
        int gi = gw * 4 + rr, b = gi >> 10, i = gi & 1023;
        const ushort* row = Out + ((size_t)b * N1 + i) * 768 + 384;
        float acc = 0.f;
        for (int c = lane; c < CC; c += 64) acc += bf2f(row[c]) * keos[c];
#pragma unroll
        for (int o = 32; o; o >>= 1) acc += __shfl_down(acc, o);
        if (lane == 0) nbL[((size_t)b * N1 + i) * NBL_LD + 1024] = f2bf(acc * INV_SCALE);
    }
}

// 10) row softmax from bf16 logits: write fp32 nb (d_out) + (max, invsum) stats
__global__ __launch_bounds__(256) void k_softnb2(
    const ushort* __restrict__ nbL, float* __restrict__ nb, float2* __restrict__ stats)
{
    int bi = blockIdx.x;
    int b = bi >> 10, i = bi & 1023;
    const ushort* row = nbL + ((size_t)b * N1 + i) * NBL_LD;
    int tid = threadIdx.x;
    uint2 u = *(const uint2*)(row + tid * 4);
    float v0 = bf2f(u.x & 0xffffu), v1 = bf2f(u.x >> 16);
    float v2 = bf2f(u.y & 0xffffu), v3 = bf2f(u.y >> 16);
    float vt = (tid == 0) ? bf2f(row[1024]) : -1e30f;
    __shared__ float r1[4]; __shared__ float bc;
    float lm = fmaxf(fmaxf(fmaxf(v0, v1), fmaxf(v2, v3)), vt);
#pragma unroll
    for (int o = 32; o; o >>= 1) lm = fmaxf(lm, __shfl_down(lm, o));
    if ((tid & 63) == 0) r1[tid >> 6] = lm;
    __syncthreads();
    if (tid == 0) bc = fmaxf(fmaxf(r1[0], r1[1]), fmaxf(r1[2], r1[3]));
    __syncthreads();
    float m = bc;
    float e0 = __expf(v0 - m), e1 = __expf(v1 - m), e2 = __expf(v2 - m), e3 = __expf(v3 - m);
    float et = (tid == 0) ? __expf(vt - m) : 0.f;
    float s = e0 + e1 + e2 + e3 + et;
#pragma unroll
    for (int o = 32; o; o >>= 1) s += __shfl_down(s, o);
    if ((tid & 63) == 0) r1[tid >> 6] = s;
    __syncthreads();
    if (tid == 0) bc = r1[0] + r1[1] + r1[2] + r1[3];
    __syncthreads();
    float inv = 1.f / bc;
    float* orow = nb + ((size_t)b * N1 + i) * N1;
    float4 ov = make_float4(e0 * inv, e1 * inv, e2 * inv, e3 * inv);
    *(float4*)(orow + tid * 4) = ov;
    if (tid == 0) { orow[1024] = et * inv; stats[b * 1024 + i] = make_float2(m, inv); }
}

// 11) one-hot row 1024 of nb (d_out)
__global__ void k_onehot(float* __restrict__ nb)
{
    int b = blockIdx.x;
    float* row = nb + ((size_t)b * N1 + NN) * N1;
    for (int j = threadIdx.x; j < N1; j += 256)
        row[j] = (j == 1024) ? 1.f : 0.f;
}

// 12) transpose: nbL (bf16 logits) + stats -> nbT bf16 [b][j][n] (probabilities)
__global__ __launch_bounds__(256) void k_transq(
    const ushort* __restrict__ nbL, const float2* __restrict__ stats,
    ushort* __restrict__ nbT)
{
    int b = blockIdx.z, n0 = blockIdx.x * 64, j0 = blockIdx.y * 64;
    __shared__ ushort tile[64][80];   // [j_local][n_local]
    __shared__ float2 st[64];
    int tid = threadIdx.x;
    if (tid < 64) st[tid] = stats[b * 1024 + n0 + tid];
    __syncthreads();
#pragma unroll
    for (int q = 0; q < 2; q++) {
        int idx = q * 256 + tid, rl = idx >> 3, ch = idx & 7;  // rl = n_local
        const ushort* src = nbL + ((size_t)b * N1 + n0 + rl) * NBL_LD + j0 + ch * 8;
        uint4 u = *(const uint4*)src;
        float2 s = st[rl];
        const ushort* us = (const ushort*)&u;
#pragma unroll
        for (int k = 0; k < 8; k++)
            tile[ch * 8 + k][rl] = f2bf(__expf(bf2f(us[k]) - s.x) * s.y);
    }
    __syncthreads();
#pragma unroll
    for (int q = 0; q < 2; q++) {
        int idx = q * 256 + tid, jl = idx >> 3, seg = idx & 7;
        int j = j0 + jl;
        if (j <= 1024) {
            uint4 v = *(const uint4*)&tile[jl][seg * 8];
            *(uint4*)(nbT + ((size_t)b * N1 + j) * NBTS + n0 + seg * 8) = v;
        }
    }
}

// 12b) quantize nbT rows (n<1024) to int8 with per-row scale s_j = rowmax/127.
// One row per wave; lane holds 16 contiguous elements (matches k_step5 layout).
__global__ __launch_bounds__(256) void k_quant(
    const ushort* __restrict__ nbT, unsigned char* __restrict__ nbQ,
    float* __restrict__ scl)
{
    int b = blockIdx.y;
    int j = blockIdx.x * 4 + (threadIdx.x >> 6);
    int lane = threadIdx.x & 63;
    if (j > 1024) return;
    const ushort* row = nbT + ((size_t)b * N1 + j) * NBTS;
    uint4 v0 = *(const uint4*)(row + lane * 16);
    uint4 v1 = *(const uint4*)(row + lane * 16 + 8);
    const ushort* u0 = (const ushort*)&v0;
    const ushort* u1 = (const ushort*)&v1;
    float p[16];
#pragma unroll
    for (int e = 0; e < 8; ++e) { p[e] = bf2f(u0[e]); p[8 + e] = bf2f(u1[e]); }
    float m = 0.f;
#pragma unroll
    for (int e = 0; e < 16; ++e) m = fmaxf(m, p[e]);
#pragma unroll
    for (int o = 32; o; o >>= 1) m = fmaxf(m, __shfl_xor(m, o));
    m = fmaxf(m, 1e-20f);
    float rcp = 127.f / m;
    uint w[4];
#pragma unroll
    for (int q = 0; q < 4; ++q) {
        uint r = 0;
#pragma unroll
        for (int k = 0; k < 4; ++k) {
            uint qv = (uint)(p[q * 4 + k] * rcp + 0.5f);
            r |= qv << (8 * k);
        }
        w[q] = r;
    }
    *(uint4*)(nbQ + ((size_t)b * N1 + j) * NBQS + lane * 16) =
        make_uint4(w[0], w[1], w[2], w[3]);
    if (lane == 0) scl[(size_t)b * 1056 + j] = m * (1.f / 127.f);
}

// 13a) init recurrence: cmd_0 = expm1(1 * start_map), total sum into psum slot 0
__global__ __launch_bounds__(256) void k_cmd0(
    const float* __restrict__ cmaps, float* __restrict__ cmd_out, float* __restrict__ ps_out)
{
    int b = blockIdx.x, tid = threadIdx.x;
    __shared__ float red[4];
    const float* m = cmaps + (size_t)b * TT * N1;
    float s = 0.f;
    for (int n = tid; n < N1; n += 256) {
        float c = expm1f(m[n]);
        cmd_out[(size_t)b * 1056 + n] = c;
        s += c;
    }
#pragma unroll
    for (int o = 32; o; o >>= 1) s += __shfl_down(s, o);
    if ((tid & 63) == 0) red[tid >> 6] = s;
    __syncthreads();
    if (tid == 0) ps_out[b * 128] = red[0] + red[1] + red[2] + red[3];
    else if (tid < 128) ps_out[b * 128 + tid] = 0.f;
}

// 13b) one recurrence step on int8 rows: 17 blocks/batch x 256 thr.
// Wave owns 16 rows (1 uint4/lane/row, 16 in flight); lane covers 16
// contiguous n; cmd in 16 registers; dequant scale applied at epilogue;
// one-hot diagonal (ctail) analytic as before.
__global__ __launch_bounds__(256) void k_step5(
    float* __restrict__ cmaps, const unsigned char* __restrict__ nbQ,
    const float* __restrict__ scl,
    const float* __restrict__ cmd_in, float* __restrict__ cmd_out,
    const float* __restrict__ ps_in, float* __restrict__ ps_out, int t)
{
    int b = blockIdx.y, blk = blockIdx.x;
    int tid = threadIdx.x, wave = tid >> 6, lane = tid & 63;
    int j0 = blk * 64 + wave * 16;
    const unsigned char* base = nbQ + (size_t)b * N1 * NBQS;

    uint4 rv[16];
#pragma unroll
    for (int r = 0; r < 16; ++r) {
        int j = j0 + r; if (j > 1024) j = 1024;   // clamp; writes masked later
        rv[r] = *(const uint4*)(base + (size_t)j * NBQS + lane * 16);
    }
    const float* ci = cmd_in + (size_t)b * 1056;
    float cC[16];
#pragma unroll
    for (int q = 0; q < 4; ++q)
        *(float4*)&cC[q * 4] = *(const float4*)(ci + lane * 16 + q * 4);
    float ctail = ci[1024];

    __shared__ float sred;
    __shared__ float red[4];
    if (wave == 0) {
        float pv = (lane < 17) ? ps_in[b * 128 + lane] : 0.f;
#pragma unroll
        for (int o = 16; o; o >>= 1) pv += __shfl_down(pv, o);
        if (lane == 0) sred = pv;
    }

    float acc[16];
#pragma unroll
    for (int r = 0; r < 16; ++r) {
        float a = 0.f;
        const uint* w = (const uint*)&rv[r];
#pragma unroll
        for (int q = 0; q < 4; ++q) {
            uint v = w[q];
            a += (float)(v & 255u)         * cC[q * 4 + 0];
            a += (float)((v >> 8) & 255u)  * cC[q * 4 + 1];
            a += (float)((v >> 16) & 255u) * cC[q * 4 + 2];
            a += (float)(v >> 24)          * cC[q * 4 + 3];
        }
#pragma unroll
        for (int o = 32; o; o >>= 1) a += __shfl_down(a, o);
        acc[r] = a;
    }
    __syncthreads();
    float inv = 1.f / sred;
    int kkn = 3 + 2 * t; if (kkn > 16) kkn = 16;   // kk_{t+1}
    if (lane == 0) {
        float cs = 0.f;
        float* orow = cmaps + ((size_t)b * TT + t + 1) * N1;
        float* co = cmd_out + (size_t)b * 1056;
        const float* sc = scl + (size_t)b * 1056;
#pragma unroll
        for (int r = 0; r < 16; ++r) {
            int j = j0 + r;
            if (j <= 1024) {
                float s = acc[r] * sc[j] + ((j == 1024) ? ctail : 0.f);
                float mo = s * inv;
                orow[j] = mo;
                float cn = expm1f((float)kkn * mo);
                co[j] = cn;
                cs += cn;
            }
        }
        red[wave] = cs;
    }
    __syncthreads();
    if (tid == 0)
        ps_out[b * 128 + blk] = red[0] + red[1] + red[2] + red[3];
}

// 14) masks
__global__ void k_masks(const float* __restrict__ cmaps, float* __restrict__ cmask)
{
    int b = threadIdx.x;
    if (b < BB) {
        int fin = 0;
        for (int t = 0; t < TT; t++) {
            cmask[b * TT + t] = (fin == 0) ? 1.f : 0.f;
            fin += (cmaps[((size_t)b * TT + t) * N1 + 1024] > 0.6f) ? 1 : 0;
        }
    }
}

// 15) maps -> bf16 (n<1024), stride 1024
__global__ void k_mapsbf(const float* __restrict__ cmaps, ushort* __restrict__ mb)
{
    size_t i = (size_t)blockIdx.x * 256 + threadIdx.x;
    size_t bt = i >> 10; int n = (int)(i & 1023);
    mb[i] = f2bf(cmaps[bt * N1 + n]);
}

// 16) char_feats
__global__ __launch_bounds__(256) void k_cfeat(
    const ushort* __restrict__ mapsbf, const ushort* __restrict__ xb,
    const float* __restrict__ cmaps, const float* __restrict__ eos,
    const float* __restrict__ masks, float* __restrict__ cfeat)
{
    int b = blockIdx.x;
    int wave = threadIdx.x >> 6, lane = threadIdx.x & 63;
    f32x4 acc[3][6] = {};
    const ushort* Ab = mapsbf + (size_t)b * TT * 1024;
    const ushort* Bb = xb + (size_t)b * CC * NN;
    for (int k0 = 0; k0 < NN; k0 += 32) {
        int kk_ = k0 + (lane >> 4) * 8;
        bf16x8 af[3], bfr[6];
#pragma unroll
        for (int i = 0; i < 3; i++)
            af[i] = *(const bf16x8*)(Ab + (size_t)(i * 16 + (lane & 15)) * 1024 + kk_);
#pragma unroll
        for (int j = 0; j < 6; j++)
            bfr[j] = *(const bf16x8*)(Bb + (size_t)(wave * 96 + j * 16 + (lane & 15)) * NN + kk_);
#pragma unroll
        for (int i = 0; i < 3; i++)
#pragma unroll
            for (int j = 0; j < 6; j++)
                acc[i][j] = __builtin_amdgcn_mfma_f32_16x16x32_bf16(af[i], bfr[j], acc[i][j], 0, 0, 0);
    }
#pragma unroll
    for (int i = 0; i < 3; i++) {
        int tbase = i * 16 + ((lane >> 4) << 2);
#pragma unroll
        for (int j = 0; j < 6; j++) {
            int c = wave * 96 + j * 16 + (lane & 15);
            float ev = eos[c];
#pragma unroll
            for (int rr = 0; rr < 4; rr++) {
                int tt = tbase + rr;
                float mlast = cmaps[((size_t)b * TT + tt) * N1 + 1024];
                float val = (acc[i][j][rr] + mlast * ev) * masks[b * TT + tt];
                cfeat[((size_t)b * TT + tt) * CC + c] = val;
            }
        }
    }
}

// 17) logits
__global__ __launch_bounds__(128) void k_logits(
    const float* __restrict__ cfeat, const float* __restrict__ cls_w,
    const float* __restrict__ cls_b, float* __restrict__ out)
{
    int bt = blockIdx.x;
    __shared__ float row[CC];
    for (int c = threadIdx.x; c < CC; c += 128) row[c] = cfeat[(size_t)bt * CC + c];
    __syncthreads();
    int j = threadIdx.x;
    if (j < NCLS) {
        float acc = cls_b[j];
        const float* w = cls_w + (size_t)j * CC;
        for (int c = 0; c < CC; c++) acc += row[c] * w[c];
        out[(size_t)bt * NCLS + j] = acc;
    }
}

extern "C" void kernel_launch(void* const* d_in, const int* in_sizes, int n_in,
                              void* d_out, int out_size, void* d_ws, size_t ws_size,
                              hipStream_t stream)
{
    (void)in_sizes; (void)n_in; (void)out_size; (void)ws_size;
    const float* x     = (const float*)d_in[0];
    const float* eos   = (const float*)d_in[1];
    const float* q_w   = (const float*)d_in[2];
    const float* q_b   = (const float*)d_in[3];
    const float* k_w   = (const float*)d_in[4];
    const float* k_b   = (const float*)d_in[5];
    const float* nav_w = (const float*)d_in[6];
    const float* cls_w = (const float*)d_in[8];
    const float* cls_b = (const float*)d_in[9];
    // nav_b (d_in[7]) is a constant shift before softmax -> no effect on outputs

    char* ws = (char*)d_ws;
    ushort* xb     = (ushort*)(ws + OFF_XB);
    ushort* Wgem   = (ushort*)(ws + OFF_WGEM);
    float*  bias   = (float*)(ws + OFF_BIAS);
    float*  g      = (float*)(ws + OFF_G);
    float*  qstart = (float*)(ws + OFF_QSTART);
    float*  keos   = (float*)(ws + OFF_KEOS);
    float2* stats  = (float2*)(ws + OFF_STATS);
    ushort* mapsbf = (ushort*)(ws + OFF_MAPSBF);
    float*  cmdbuf = (float*)(ws + OFF_CMD);    // 2 x 33792 floats
    float*  psbuf  = (float*)(ws + OFF_PSUM);   // 2 x 4096 floats
    ushort* xbT    = (ushort*)(ws + OFF_XBT);
    ushort* nbL    = (ushort*)(ws + OFF_NBL);
    unsigned char* nbQ = (unsigned char*)(ws + OFF_NBQ);
    float*  scl    = (float*)(ws + OFF_SCL);
    ushort* Out    = (ushort*)(ws + OFF_OUT);
    ushort* nbT    = (ushort*)(ws + OFF_NBT);

    float* out     = (float*)d_out;
    float* logits  = out + OFF_LOGITS;
    float* cfeat   = out + OFF_CFEAT;
    float* cmaps   = out + OFF_CMAPS;
    float* cmask   = out + OFF_CMASK;
    float* nb      = out + OFF_NB;

    k_conv_mean<<<3072, 256, 0, stream>>>(x, xb, g);
    k_transpose<<<dim3(6, 16, BB), 256, 0, stream>>>(xb, xbT);
    k_setup<<<833, 384, 0, stream>>>(k_w, k_b, nav_w, q_w, q_b, eos, g,
                                     Wgem, bias, xbT, keos, Out, qstart);

    // Out[:, :1024, :768] = xt @ [k_w | W2]^T + bias (kfeat | tmp), bf16
    k_gemm<0, 6, 48><<<1536, 256, 0, stream>>>(
        xbT, (size_t)N1 * CC, CC, Wgem, 0, CC, Out, (size_t)N1 * 768, 768, bias);

    k_start<<<BB, 1024, 0, stream>>>(Out, qstart, cmaps);
    k_cmd0<<<BB, 256, 0, stream>>>(cmaps, cmdbuf, psbuf);
    k_eoscol_nbl<<<2048, 256, 0, stream>>>(Out, keos, nbL);

    // nb logits (cols 0..1023) = tmp @ kfeat^T / scale, bf16 into nbL (ld 1088)
    k_gemm<1, 8, 64><<<2048, 256, 0, stream>>>(
        Out + 384, (size_t)N1 * 768, 768, Out, (size_t)N1 * 768, 768,
        nbL, (size_t)N1 * NBL_LD, NBL_LD, nullptr);

    k_softnb2<<<BB * NN, 256, 0, stream>>>(nbL, nb, stats);
    k_onehot<<<BB, 256, 0, stream>>>(nb);
    k_transq<<<dim3(16, 17, BB), 256, 0, stream>>>(nbL, stats, nbT);
    k_quant<<<dim3(257, BB), 256, 0, stream>>>(nbT, nbQ, scl);

    // 47 recurrence steps on int8 rows with cmd/psum carry
    for (int t = 0; t < TT - 1; t++)
        k_step5<<<dim3(17, BB), 256, 0, stream>>>(
            cmaps, nbQ, scl,
            cmdbuf + (size_t)(t & 1) * 33792, cmdbuf + (size_t)((t + 1) & 1) * 33792,
            psbuf + (size_t)(t & 1) * 4096,  psbuf + (size_t)((t + 1) & 1) * 4096, t);

    k_masks<<<1, 64, 0, stream>>>(cmaps, cmask);
    k_mapsbf<<<6144, 256, 0, stream>>>(cmaps, mapsbf);
    k_cfeat<<<BB, 256, 0, stream>>>(mapsbf, xb, cmaps, eos, cmask, cfeat);
    k_logits<<<BB * TT, 128, 0, stream>>>(cfeat, cls_w, cls_b, logits);
}